// Round 1
// baseline (311.942 us; speedup 1.0000x reference)
//
#include <hip/hip_runtime.h>
#include <hip/hip_bf16.h>

#define N_ROWS   262144
#define PASS_BLOCKS 512
#define TPW 2                     // 64-row tiles per wave
#define LN_EPS_F 1e-3f
#define EPS_W    1e-8f
#define NEPS_F   (262144.0f*1e-8f)

typedef __hip_bfloat16 bf16;

__device__ __forceinline__ float bl2f(unsigned u){ return __uint_as_float(u<<16); }
__device__ __forceinline__ float bh2f(unsigned u){ return __uint_as_float(u & 0xffff0000u); }

__device__ __forceinline__ float wave_sum64(float v){
#pragma unroll
  for (int off=1; off<64; off<<=1) v += __shfl_xor(v, off);
  return v;
}

// ---------------- LayerNorm(x) then K = xn@Wk, V = xn@Wv (bf16 out) ----------------
__global__ __launch_bounds__(256, 2) void lnkv_kernel(
    const float* __restrict__ x, const float* __restrict__ g, const float* __restrict__ b,
    const float* __restrict__ Wk, const float* __restrict__ Wv,
    bf16* __restrict__ K, bf16* __restrict__ V)
{
  __shared__ __align__(16) float xs_pool[4][4096];
  const int w  = threadIdx.x >> 6;
  const int ln = threadIdx.x & 63;
  float* xs = xs_pool[w];

  // per-thread weight columns (output dim = ln)
  float wk[64], wv[64];
#pragma unroll
  for (int c = 0; c < 64; ++c) { wk[c] = Wk[c*64 + ln]; wv[c] = Wv[c*64 + ln]; }
  const int cc0 = ln & 15;
  const float4 g4 = *(const float4*)&g[cc0*4];
  const float4 b4 = *(const float4*)&b[cc0*4];

  const int gw = blockIdx.x*4 + w;
  for (int i = 0; i < TPW; ++i) {
    const int tile = gw*TPW + i;
    const long r0 = (long)tile*64;
    // load x tile, LN per row (16-lane groups own a row), write rotated chunks to LDS
#pragma unroll
    for (int it = 0; it < 16; ++it) {
      int r = it*4 + (ln>>4);
      float4 xv = *(const float4*)&x[(r0 + r)*64 + cc0*4];
      float s1 = xv.x+xv.y+xv.z+xv.w;
      float s2 = xv.x*xv.x+xv.y*xv.y+xv.z*xv.z+xv.w*xv.w;
      s1 += __shfl_xor(s1,1); s2 += __shfl_xor(s2,1);
      s1 += __shfl_xor(s1,2); s2 += __shfl_xor(s2,2);
      s1 += __shfl_xor(s1,4); s2 += __shfl_xor(s2,4);
      s1 += __shfl_xor(s1,8); s2 += __shfl_xor(s2,8);
      float m  = s1*(1.0f/64.0f);
      float var= s2*(1.0f/64.0f) - m*m;
      float rs = rsqrtf(var + LN_EPS_F);
      float4 xn;
      xn.x = (xv.x-m)*rs*g4.x + b4.x;
      xn.y = (xv.y-m)*rs*g4.y + b4.y;
      xn.z = (xv.z-m)*rs*g4.z + b4.z;
      xn.w = (xv.w-m)*rs*g4.w + b4.w;
      *(float4*)&xs[r*64 + (((cc0 + r)&15)<<2)] = xn;   // rotation swizzle: conflict-free
    }
    __syncthreads();
    // matvec: thread = output dim ln; broadcast-read xn row chunks
    for (int r = 0; r < 64; ++r) {
      float ak0=0.f, ak1=0.f, av0=0.f, av1=0.f;
      const int rb = r*64, rm = r & 15;
#pragma unroll
      for (int cc = 0; cc < 16; ++cc) {
        float4 xn4 = *(const float4*)&xs[rb + (((cc + rm)&15)<<2)];
        if (cc & 1) {
          ak1 = fmaf(xn4.x, wk[cc*4+0], ak1); ak1 = fmaf(xn4.y, wk[cc*4+1], ak1);
          ak1 = fmaf(xn4.z, wk[cc*4+2], ak1); ak1 = fmaf(xn4.w, wk[cc*4+3], ak1);
          av1 = fmaf(xn4.x, wv[cc*4+0], av1); av1 = fmaf(xn4.y, wv[cc*4+1], av1);
          av1 = fmaf(xn4.z, wv[cc*4+2], av1); av1 = fmaf(xn4.w, wv[cc*4+3], av1);
        } else {
          ak0 = fmaf(xn4.x, wk[cc*4+0], ak0); ak0 = fmaf(xn4.y, wk[cc*4+1], ak0);
          ak0 = fmaf(xn4.z, wk[cc*4+2], ak0); ak0 = fmaf(xn4.w, wk[cc*4+3], ak0);
          av0 = fmaf(xn4.x, wv[cc*4+0], av0); av0 = fmaf(xn4.y, wv[cc*4+1], av0);
          av0 = fmaf(xn4.z, wv[cc*4+2], av0); av0 = fmaf(xn4.w, wv[cc*4+3], av0);
        }
      }
      K[(r0 + r)*64 + ln] = __float2bfloat16(ak0+ak1);
      V[(r0 + r)*64 + ln] = __float2bfloat16(av0+av1);
    }
    __syncthreads();
  }
}

// ---------------- one slot-attention data pass over K,V ----------------
// computes per-block partials: numer[4][64] = sum(attn_j * v_d), vsum[64], colsum[4]
__global__ __launch_bounds__(256, 2) void attn_pass_kernel(
    const bf16* __restrict__ K, const bf16* __restrict__ V,
    const float* __restrict__ qT, float* __restrict__ partial,
    float* __restrict__ attn_out, int last)
{
  __shared__ __align__(16) float pool[4][4352];
  __shared__ __align__(16) float attn_s[4][64][4];
  __shared__ __align__(16) float qT_s[256];
  const int w  = threadIdx.x >> 6;
  const int ln = threadIdx.x & 63;
  float* buf = pool[w];
  qT_s[threadIdx.x] = qT[threadIdx.x];
  __syncthreads();

  float n0=0,n1=0,n2=0,n3=0, vsacc=0;
  float cs0=0,cs1=0,cs2=0,cs3=0;

  const int gw = blockIdx.x*4 + w;
  for (int i = 0; i < TPW; ++i) {
    const int tile = gw*TPW + i;
    const long r0 = (long)tile*64;
    // ---- K tile -> transposed + rotation-swizzled fp32 in LDS ----
#pragma unroll
    for (int it = 0; it < 8; ++it) {
      int r = it*8 + (ln>>3), c8 = (ln&7)*8;
      uint4 kk = *(const uint4*)&K[(r0+r)*64 + c8];
      buf[(c8+0)*64 + ((r + c8+0)&63)] = bl2f(kk.x);
      buf[(c8+1)*64 + ((r + c8+1)&63)] = bh2f(kk.x);
      buf[(c8+2)*64 + ((r + c8+2)&63)] = bl2f(kk.y);
      buf[(c8+3)*64 + ((r + c8+3)&63)] = bh2f(kk.y);
      buf[(c8+4)*64 + ((r + c8+4)&63)] = bl2f(kk.z);
      buf[(c8+5)*64 + ((r + c8+5)&63)] = bh2f(kk.z);
      buf[(c8+6)*64 + ((r + c8+6)&63)] = bl2f(kk.w);
      buf[(c8+7)*64 + ((r + c8+7)&63)] = bh2f(kk.w);
    }
    __syncthreads();
    // ---- logits + softmax (thread = row = ln) ----
    float l0=0,l1=0,l2=0,l3=0;
#pragma unroll 8
    for (int d = 0; d < 64; ++d) {
      float kd = buf[d*64 + ((ln + d)&63)];
      float4 q4 = *(const float4*)&qT_s[d*4];
      l0 = fmaf(kd, q4.x, l0); l1 = fmaf(kd, q4.y, l1);
      l2 = fmaf(kd, q4.z, l2); l3 = fmaf(kd, q4.w, l3);
    }
    float mx = fmaxf(fmaxf(l0,l1), fmaxf(l2,l3));
    float e0 = __expf(l0-mx), e1 = __expf(l1-mx), e2 = __expf(l2-mx), e3 = __expf(l3-mx);
    float inv = 1.0f/(e0+e1+e2+e3);
    float a0=e0*inv, a1=e1*inv, a2=e2*inv, a3=e3*inv;
    cs0 += a0; cs1 += a1; cs2 += a2; cs3 += a3;
    if (last) {
      attn_out[(long)0*N_ROWS + r0 + ln] = a0;
      attn_out[(long)1*N_ROWS + r0 + ln] = a1;
      attn_out[(long)2*N_ROWS + r0 + ln] = a2;
      attn_out[(long)3*N_ROWS + r0 + ln] = a3;
    }
    float4 av4; av4.x=a0; av4.y=a1; av4.z=a2; av4.w=a3;
    *(float4*)&attn_s[w][ln][0] = av4;
    __syncthreads();
    // ---- V tile -> row layout stride 68 ----
#pragma unroll
    for (int it = 0; it < 8; ++it) {
      int r = it*8 + (ln>>3), c8 = (ln&7)*8;
      uint4 vv = *(const uint4*)&V[(r0+r)*64 + c8];
      float4 p0, p1;
      p0.x = bl2f(vv.x); p0.y = bh2f(vv.x); p0.z = bl2f(vv.y); p0.w = bh2f(vv.y);
      p1.x = bl2f(vv.z); p1.y = bh2f(vv.z); p1.z = bl2f(vv.w); p1.w = bh2f(vv.w);
      *(float4*)&buf[r*68 + c8]     = p0;
      *(float4*)&buf[r*68 + c8 + 4] = p1;
    }
    __syncthreads();
    // ---- accumulate numerators (thread = dim = ln) ----
#pragma unroll 8
    for (int r = 0; r < 64; ++r) {
      float4 a4 = *(const float4*)&attn_s[w][r][0];
      float vvv = buf[r*68 + ln];
      n0 = fmaf(a4.x, vvv, n0); n1 = fmaf(a4.y, vvv, n1);
      n2 = fmaf(a4.z, vvv, n2); n3 = fmaf(a4.w, vvv, n3);
      vsacc += vvv;
    }
    __syncthreads();
  }

  // ---- block reduction (deterministic) ----
  cs0 = wave_sum64(cs0); cs1 = wave_sum64(cs1);
  cs2 = wave_sum64(cs2); cs3 = wave_sum64(cs3);
  float* fp = &pool[0][0];
  __syncthreads();
  fp[w*256 + 0*64 + ln] = n0;
  fp[w*256 + 1*64 + ln] = n1;
  fp[w*256 + 2*64 + ln] = n2;
  fp[w*256 + 3*64 + ln] = n3;
  fp[1024 + w*64 + ln] = vsacc;
  if (ln == 0) { fp[1280+w*4+0]=cs0; fp[1280+w*4+1]=cs1; fp[1280+w*4+2]=cs2; fp[1280+w*4+3]=cs3; }
  __syncthreads();
  const int t = threadIdx.x;
  partial[blockIdx.x*324 + t] = fp[t] + fp[256+t] + fp[512+t] + fp[768+t];
  if (t < 64)
    partial[blockIdx.x*324 + 256 + t] = fp[1024+t] + fp[1088+t] + fp[1152+t] + fp[1216+t];
  if (t < 4)
    partial[blockIdx.x*324 + 320 + t] = fp[1280+t] + fp[1284+t] + fp[1288+t] + fp[1292+t];
}

// ---------------- grid reduce of per-block partials ----------------
__global__ void reduce_kernel(const float* __restrict__ partial, float* __restrict__ red) {
  const int i = blockIdx.x, ln = threadIdx.x;
  float acc = 0.f;
  for (int b = ln; b < PASS_BLOCKS; b += 64) acc += partial[b*324 + i];
  acc = wave_sum64(acc);
  if (ln == 0) red[i] = acc;
}

// ---------------- slot init / GRU+MLP update / q computation (1 block) ----------------
__global__ void update_kernel(int mode, const float* __restrict__ red,
    float* __restrict__ slots, float* __restrict__ qT, float* __restrict__ out,
    const float* __restrict__ noise_fg, const float* __restrict__ noise_bg,
    const float* __restrict__ mu_fg, const float* __restrict__ ls_fg,
    const float* __restrict__ mu_bg, const float* __restrict__ ls_bg,
    const float* __restrict__ qfg_g, const float* __restrict__ qfg_b, const float* __restrict__ Wq_fg,
    const float* __restrict__ qbg_g, const float* __restrict__ qbg_b, const float* __restrict__ Wq_bg,
    const float* __restrict__ gfWx, const float* __restrict__ gfWh,
    const float* __restrict__ gfbin, const float* __restrict__ gfbrec,
    const float* __restrict__ gbWx, const float* __restrict__ gbWh,
    const float* __restrict__ gbbin, const float* __restrict__ gbbrec,
    const float* __restrict__ mfg_g, const float* __restrict__ mfg_b,
    const float* __restrict__ mfW1, const float* __restrict__ mfb1,
    const float* __restrict__ mfW2, const float* __restrict__ mfb2,
    const float* __restrict__ mbg_g, const float* __restrict__ mbg_b,
    const float* __restrict__ mbW1, const float* __restrict__ mbb1,
    const float* __restrict__ mbW2, const float* __restrict__ mbb2)
{
  const int t = threadIdx.x, j = t>>6, ln = t&63;
  const bool bg = (j==0);
  __shared__ float h_s[4][64], u_s[4][64], gx_s[4][192], gh_s[4][192], l_s[4][64], h1_s[4][128];
  float hnew;
  if (mode == 0) {
    hnew = bg ? fmaf(expf(ls_bg[ln]), noise_bg[ln], mu_bg[ln])
              : fmaf(expf(ls_fg[ln]), noise_fg[(j-1)*64+ln], mu_fg[ln]);
  } else {
    float h = slots[j*64+ln];
    h_s[j][ln] = h;
    float csum = red[320+j] + NEPS_F;
    u_s[j][ln] = (red[j*64+ln] + EPS_W*red[256+ln]) / csum;
    __syncthreads();
    const float* Wx = bg?gbWx:gfWx; const float* Wh = bg?gbWh:gfWh;
    const float* bi = bg?gbbin:gfbin; const float* br = bg?gbbrec:gfbrec;
#pragma unroll
    for (int gi=0; gi<3; ++gi) {
      const int gcol = gi*64+ln;
      float ax = bi[gcol], ah = br[gcol];
#pragma unroll
      for (int d=0; d<64; ++d) {
        ax = fmaf(u_s[j][d], Wx[d*192+gcol], ax);
        ah = fmaf(h_s[j][d], Wh[d*192+gcol], ah);
      }
      gx_s[j][gcol]=ax; gh_s[j][gcol]=ah;
    }
    __syncthreads();
    float z  = 1.f/(1.f + expf(-(gx_s[j][ln]     + gh_s[j][ln])));
    float rr = 1.f/(1.f + expf(-(gx_s[j][64+ln]  + gh_s[j][64+ln])));
    float hc = tanhf(gx_s[j][128+ln] + rr*gh_s[j][128+ln]);
    float hg = z*h + (1.f - z)*hc;
    // MLP with LN (exact two-pass variance) + residual
    float m  = wave_sum64(hg) * (1.f/64.f);
    float vr = wave_sum64((hg-m)*(hg-m)) * (1.f/64.f);
    float rs = rsqrtf(vr + LN_EPS_F);
    l_s[j][ln] = (bg?mbg_g[ln]:mfg_g[ln])*(hg-m)*rs + (bg?mbg_b[ln]:mfg_b[ln]);
    __syncthreads();
    const float* W1 = bg?mbW1:mfW1; const float* b1 = bg?mbb1:mfb1;
#pragma unroll
    for (int hb=0; hb<2; ++hb) {
      const int hi = hb*64+ln;
      float a = b1[hi];
#pragma unroll
      for (int c=0;c<64;++c) a = fmaf(l_s[j][c], W1[c*128+hi], a);
      h1_s[j][hi] = fmaxf(a, 0.f);
    }
    __syncthreads();
    const float* W2 = bg?mbW2:mfW2; const float* b2 = bg?mbb2:mfb2;
    float o = hg + b2[ln];
#pragma unroll
    for (int hh=0; hh<128; ++hh) o = fmaf(h1_s[j][hh], W2[hh*64+ln], o);
    hnew = o;
  }
  slots[j*64+ln] = hnew;
  if (mode == 3) {
    out[j*64+ln] = hnew;
  } else {
    // q for next pass: LN(slots) @ Wq * D^-0.5, stored transposed qT[d][j]
    float m  = wave_sum64(hnew) * (1.f/64.f);
    float vr = wave_sum64((hnew-m)*(hnew-m)) * (1.f/64.f);
    float rs = rsqrtf(vr + LN_EPS_F);
    float lq = (bg?qbg_g[ln]:qfg_g[ln])*(hnew-m)*rs + (bg?qbg_b[ln]:qfg_b[ln]);
    __syncthreads();
    l_s[j][ln] = lq;
    __syncthreads();
    const float* Wq = bg?Wq_bg:Wq_fg;
    float a = 0.f;
#pragma unroll
    for (int c=0;c<64;++c) a = fmaf(l_s[j][c], Wq[c*64+ln], a);
    qT[ln*4+j] = a*0.125f;
  }
}

extern "C" void kernel_launch(void* const* d_in, const int* in_sizes, int n_in,
                              void* d_out, int out_size, void* d_ws, size_t ws_size,
                              hipStream_t stream)
{
  const float* x        = (const float*)d_in[0];
  const float* noise_fg = (const float*)d_in[1];
  const float* noise_bg = (const float*)d_in[2];
  const float* ln_g     = (const float*)d_in[3];
  const float* ln_b     = (const float*)d_in[4];
  const float* mu_fg    = (const float*)d_in[5];
  const float* ls_fg    = (const float*)d_in[6];
  const float* mu_bg    = (const float*)d_in[7];
  const float* ls_bg    = (const float*)d_in[8];
  const float* Wk       = (const float*)d_in[9];
  const float* Wv       = (const float*)d_in[10];
  const float* qfg_g    = (const float*)d_in[11];
  const float* qfg_b    = (const float*)d_in[12];
  const float* Wq_fg    = (const float*)d_in[13];
  const float* qbg_g    = (const float*)d_in[14];
  const float* qbg_b    = (const float*)d_in[15];
  const float* Wq_bg    = (const float*)d_in[16];
  const float* gfWx     = (const float*)d_in[17];
  const float* gfWh     = (const float*)d_in[18];
  const float* gfbin    = (const float*)d_in[19];
  const float* gfbrec   = (const float*)d_in[20];
  const float* gbWx     = (const float*)d_in[21];
  const float* gbWh     = (const float*)d_in[22];
  const float* gbbin    = (const float*)d_in[23];
  const float* gbbrec   = (const float*)d_in[24];
  const float* mfg_g    = (const float*)d_in[25];
  const float* mfg_b    = (const float*)d_in[26];
  const float* mfW1     = (const float*)d_in[27];
  const float* mfb1     = (const float*)d_in[28];
  const float* mfW2     = (const float*)d_in[29];
  const float* mfb2     = (const float*)d_in[30];
  const float* mbg_g    = (const float*)d_in[31];
  const float* mbg_b    = (const float*)d_in[32];
  const float* mbW1     = (const float*)d_in[33];
  const float* mbb1     = (const float*)d_in[34];
  const float* mbW2     = (const float*)d_in[35];
  const float* mbb2     = (const float*)d_in[36];

  float* out = (float*)d_out;

  // ws layout: K bf16 (32MB) | V bf16 (32MB) | slots(256) qT(256) | partial(512*324) | red(324)
  char* ws = (char*)d_ws;
  bf16* K = (bf16*)ws;
  bf16* V = (bf16*)(ws + (size_t)N_ROWS*64*2);
  float* fws     = (float*)(ws + (size_t)N_ROWS*64*4);
  float* slots   = fws;
  float* qT      = fws + 256;
  float* partial = fws + 512;
  float* red     = partial + (size_t)PASS_BLOCKS*324;

  auto launch_update = [&](int mode){
    update_kernel<<<1, 256, 0, stream>>>(mode, red, slots, qT, out,
      noise_fg, noise_bg, mu_fg, ls_fg, mu_bg, ls_bg,
      qfg_g, qfg_b, Wq_fg, qbg_g, qbg_b, Wq_bg,
      gfWx, gfWh, gfbin, gfbrec, gbWx, gbWh, gbbin, gbbrec,
      mfg_g, mfg_b, mfW1, mfb1, mfW2, mfb2,
      mbg_g, mbg_b, mbW1, mbb1, mbW2, mbb2);
  };

  lnkv_kernel<<<PASS_BLOCKS, 256, 0, stream>>>(x, ln_g, ln_b, Wk, Wv, K, V);
  launch_update(0);  // init slots + q for iter 1
  for (int it = 0; it < 3; ++it) {
    attn_pass_kernel<<<PASS_BLOCKS, 256, 0, stream>>>(K, V, qT, partial, out + 256, it==2 ? 1 : 0);
    reduce_kernel<<<324, 64, 0, stream>>>(partial, red);
    launch_update(it+1);
  }
}